// Round 1
// baseline (211.348 us; speedup 1.0000x reference)
//
#include <hip/hip_runtime.h>

#define B_SZ 8192
#define F_BASE 256

// ---------------- transpose x [8192,256] -> xT rows 0..255 ([f][b]) ----------------
__global__ __launch_bounds__(256) void ndt_transpose(const float* __restrict__ x,
                                                     float* __restrict__ xT) {
  __shared__ float tile[32][33];
  int f0 = blockIdx.x * 32;
  int b0 = blockIdx.y * 32;
  int tx = threadIdx.x, ty = threadIdx.y;
#pragma unroll
  for (int k = 0; k < 32; k += 8)
    tile[ty + k][tx] = x[(size_t)(b0 + ty + k) * F_BASE + f0 + tx];
  __syncthreads();
#pragma unroll
  for (int k = 0; k < 32; k += 8)
    xT[(size_t)(f0 + ty + k) * B_SZ + b0 + tx] = tile[tx][ty + k];
}

// ---------------- masks (exact 1.5-entmax via bisection) + fused params ----------------
struct MaskArgs {
  const float* fm[6];
  const float* cp[6];
  const float* lr[6];
  float* out_masks;  // d_out base
  float4* prm;       // fused params {c10, ml0, ml1, 0}
};

__device__ __forceinline__ float wave_max(float v) {
#pragma unroll
  for (int o = 32; o > 0; o >>= 1) v = fmaxf(v, __shfl_xor(v, o));
  return v;
}
__device__ __forceinline__ float wave_sum(float v) {
#pragma unroll
  for (int o = 32; o > 0; o >>= 1) v += __shfl_xor(v, o);
  return v;
}

__global__ __launch_bounds__(64) void ndt_masks(MaskArgs a) {
  const int maskOff[6] = {524288, 524544, 525060, 526100, 528212, 532564};
  const int prmOff[6]  = {0, 256, 772, 1812, 3924, 8276};
  int bid = blockIdx.x, lane = threadIdx.x;
  int d = 0, s = bid, n = 1;
  while (s >= n) { s -= n; n <<= 1; ++d; }   // level d, stump s, n = 2^d
  int Fd = F_BASE + ((d > 0) ? n : 0);

  const float* fm = a.fm[d] + (size_t)s * Fd;
  float y[5];
#pragma unroll
  for (int j = 0; j < 5; ++j) {
    int f = lane + 64 * j;
    y[j] = (f < Fd) ? fm[f] * 0.5f : -3.0e38f;
  }
  float m = fmaxf(fmaxf(fmaxf(y[0], y[1]), fmaxf(y[2], y[3])), y[4]);
  m = wave_max(m);
#pragma unroll
  for (int j = 0; j < 5; ++j) y[j] -= m;

  // solve sum clip(y - tau, 0)^2 = 1 ; tau in [-1, 0], strictly decreasing in tau
  float lo = -1.f, hi = 0.f;
  for (int it = 0; it < 40; ++it) {
    float tau = 0.5f * (lo + hi);
    float ss = 0.f;
#pragma unroll
    for (int j = 0; j < 5; ++j) {
      float v = fmaxf(y[j] - tau, 0.f);
      ss = __builtin_fmaf(v, v, ss);
    }
    ss = wave_sum(ss);
    if (ss >= 1.f) lo = tau; else hi = tau;
  }
  float tau = 0.5f * (lo + hi);

  float* mo = a.out_masks + maskOff[d] + (size_t)s * Fd;
  const float* cp = a.cp[d] + (size_t)s * Fd * 2;
  const float* lr = a.lr[d] + (size_t)s * Fd * 2;
  float4* pr = a.prm + prmOff[d] + (size_t)s * Fd;
#pragma unroll
  for (int j = 0; j < 5; ++j) {
    int f = lane + 64 * j;
    if (f < Fd) {
      float v = fmaxf(y[j] - tau, 0.f);
      float mk = v * v;
      mo[f] = mk;
      float c0 = cp[2 * f], c1 = cp[2 * f + 1];
      pr[f] = make_float4(c1 - c0, lr[2 * f] * mk, lr[2 * f + 1] * mk, 0.f);
    }
  }
}

// ---------------- per-level stump kernel ----------------
// 2-elem entmax15 closed form: t = c10 - x; tc = clamp(t,-2,2);
// p0 = 0.5 + tc*sqrt(0.125 - tc*tc/64); p1 = 1 - p0.
__global__ __launch_bounds__(256) void ndt_level(const float* __restrict__ xT,
                                                 const float4* __restrict__ prm,
                                                 int Fd, float* __restrict__ outp,
                                                 int isFinal) {
  int s = blockIdx.x;
  int b = blockIdx.y * 256 + threadIdx.x;
  const float4* p = prm + (size_t)s * Fd;
  const float* xp = xT + b;
  float acc0 = 0.f, acc1 = 0.f;
#pragma unroll 4
  for (int f = 0; f < Fd; ++f) {
    float xv = xp[(size_t)f * B_SZ];
    float4 c = p[f];
    float t = c.x - xv;
    float tc = __builtin_amdgcn_fmed3f(t, -2.f, 2.f);
    float u = __builtin_fmaf(tc * tc, -0.015625f, 0.125f);
    float q = __builtin_amdgcn_sqrtf(u);
    float e = tc * q;
    acc0 = __builtin_fmaf(0.5f + e, c.y, acc0);
    acc1 = __builtin_fmaf(0.5f - e, c.z, acc1);
  }
  if (isFinal) {
    float* o = outp + (size_t)b * 64 + 2 * s;
    o[0] = acc0;
    o[1] = acc1;
  } else {
    outp[(size_t)(2 * s) * B_SZ + b] = acc0;
    outp[(size_t)(2 * s + 1) * B_SZ + b] = acc1;
  }
}

extern "C" void kernel_launch(void* const* d_in, const int* in_sizes, int n_in,
                              void* d_out, int out_size, void* d_ws, size_t ws_size,
                              hipStream_t stream) {
  const float* x = (const float*)d_in[0];
  float* out = (float*)d_out;
  float* xT = (float*)d_ws;                                   // [288][8192] f32
  float4* prm = (float4*)((char*)d_ws + (size_t)288 * B_SZ * 4);

  hipLaunchKernelGGL(ndt_transpose, dim3(F_BASE / 32, B_SZ / 32), dim3(32, 8), 0,
                     stream, x, xT);

  MaskArgs ma;
  for (int d = 0; d < 6; ++d) {
    ma.fm[d] = (const float*)d_in[1 + 3 * d];
    ma.cp[d] = (const float*)d_in[2 + 3 * d];
    ma.lr[d] = (const float*)d_in[3 + 3 * d];
  }
  ma.out_masks = out;
  ma.prm = prm;
  hipLaunchKernelGGL(ndt_masks, dim3(63), dim3(64), 0, stream, ma);

  const int FdArr[6] = {256, 258, 260, 264, 272, 288};
  const int prmOff[6] = {0, 256, 772, 1812, 3924, 8276};
  float* interm = xT + (size_t)256 * B_SZ;  // rows 256.. hold prev-level out (transposed)

  for (int d = 0; d < 6; ++d) {
    int n = 1 << d;
    int isFinal = (d == 5) ? 1 : 0;
    float* outp = isFinal ? out : interm;
    hipLaunchKernelGGL(ndt_level, dim3(n, B_SZ / 256), dim3(256), 0, stream, xT,
                       prm + prmOff[d], FdArr[d], outp, isFinal);
  }
}

// Round 2
// 118.047 us; speedup vs baseline: 1.7904x; 1.7904x over previous
//
#include <hip/hip_runtime.h>

#define B_SZ 8192
#define F_BASE 256

// ---------------- transpose x [8192,256] -> xT rows 0..255 ([f][b]) ----------------
__global__ __launch_bounds__(256) void ndt_transpose(const float* __restrict__ x,
                                                     float* __restrict__ xT) {
  __shared__ float tile[32][33];
  int f0 = blockIdx.x * 32;
  int b0 = blockIdx.y * 32;
  int tx = threadIdx.x, ty = threadIdx.y;
#pragma unroll
  for (int k = 0; k < 32; k += 8)
    tile[ty + k][tx] = x[(size_t)(b0 + ty + k) * F_BASE + f0 + tx];
  __syncthreads();
#pragma unroll
  for (int k = 0; k < 32; k += 8)
    xT[(size_t)(f0 + ty + k) * B_SZ + b0 + tx] = tile[tx][ty + k];
}

// ---------------- masks (exact 1.5-entmax via bisection) + fused params ----------------
struct MaskArgs {
  const float* fm[6];
  const float* cp[6];
  const float* lr[6];
  float* out_masks;  // d_out base
  float4* prm;       // fused params {c10, ml0, ml1, 0}
  float2* cst;       // per-stump {0.5*sum(ml0), 0.5*sum(ml1)}
};

__device__ __forceinline__ float wave_max(float v) {
#pragma unroll
  for (int o = 32; o > 0; o >>= 1) v = fmaxf(v, __shfl_xor(v, o));
  return v;
}
__device__ __forceinline__ float wave_sum(float v) {
#pragma unroll
  for (int o = 32; o > 0; o >>= 1) v += __shfl_xor(v, o);
  return v;
}

__global__ __launch_bounds__(64) void ndt_masks(MaskArgs a) {
  const int maskOff[6] = {524288, 524544, 525060, 526100, 528212, 532564};
  const int prmOff[6]  = {0, 256, 772, 1812, 3924, 8276};
  const int cstOff[6]  = {0, 1, 3, 7, 15, 31};
  int bid = blockIdx.x, lane = threadIdx.x;
  int d = 0, s = bid, n = 1;
  while (s >= n) { s -= n; n <<= 1; ++d; }   // level d, stump s, n = 2^d
  int Fd = F_BASE + ((d > 0) ? n : 0);

  const float* fm = a.fm[d] + (size_t)s * Fd;
  float y[5];
#pragma unroll
  for (int j = 0; j < 5; ++j) {
    int f = lane + 64 * j;
    y[j] = (f < Fd) ? fm[f] * 0.5f : -3.0e38f;
  }
  float m = fmaxf(fmaxf(fmaxf(y[0], y[1]), fmaxf(y[2], y[3])), y[4]);
  m = wave_max(m);
#pragma unroll
  for (int j = 0; j < 5; ++j) y[j] -= m;

  // solve sum clip(y - tau, 0)^2 = 1 ; tau in [-1, 0], strictly decreasing in tau
  float lo = -1.f, hi = 0.f;
  for (int it = 0; it < 40; ++it) {
    float tau = 0.5f * (lo + hi);
    float ss = 0.f;
#pragma unroll
    for (int j = 0; j < 5; ++j) {
      float v = fmaxf(y[j] - tau, 0.f);
      ss = __builtin_fmaf(v, v, ss);
    }
    ss = wave_sum(ss);
    if (ss >= 1.f) lo = tau; else hi = tau;
  }
  float tau = 0.5f * (lo + hi);

  float* mo = a.out_masks + maskOff[d] + (size_t)s * Fd;
  const float* cp = a.cp[d] + (size_t)s * Fd * 2;
  const float* lr = a.lr[d] + (size_t)s * Fd * 2;
  float4* pr = a.prm + prmOff[d] + (size_t)s * Fd;
  float sum0 = 0.f, sum1 = 0.f;
#pragma unroll
  for (int j = 0; j < 5; ++j) {
    int f = lane + 64 * j;
    if (f < Fd) {
      float v = fmaxf(y[j] - tau, 0.f);
      float mk = v * v;
      mo[f] = mk;
      float c0 = cp[2 * f], c1 = cp[2 * f + 1];
      float ml0 = lr[2 * f] * mk, ml1 = lr[2 * f + 1] * mk;
      sum0 += ml0;
      sum1 += ml1;
      pr[f] = make_float4(c1 - c0, ml0, ml1, 0.f);
    }
  }
  sum0 = wave_sum(sum0);
  sum1 = wave_sum(sum1);
  if (lane == 0) a.cst[cstOff[d] + s] = make_float2(0.5f * sum0, 0.5f * sum1);
}

// 2-elem entmax15 closed form: t = c10 - x; tc = clamp(t,-2,2);
// e = tc*sqrt(0.125 - tc^2/64); p0 = 0.5+e, p1 = 0.5-e.
__device__ __forceinline__ float entpair(float c10, float xv) {
  float t = c10 - xv;
  float tc = __builtin_amdgcn_fmed3f(t, -2.f, 2.f);
  float u = __builtin_fmaf(tc * tc, -0.015625f, 0.125f);
  return tc * __builtin_amdgcn_sqrtf(u);
}

// ---------------- small levels (d=0..3): wave per batch row, lanes over features --------
// WRT=0: write b-major [b][2*NS]; WRT=1: write transposed rows [2s][b]
template <int NS, int FD, int WRT>
__global__ __launch_bounds__(256) void ndt_small(const float* __restrict__ x,
                                                 const float* __restrict__ prevB,
                                                 const float4* __restrict__ prm,
                                                 const float2* __restrict__ cst,
                                                 float* __restrict__ outp) {
  __shared__ float4 lds[NS * FD];
  int tid = threadIdx.x;
  for (int i = tid; i < NS * FD; i += 256) lds[i] = prm[i];
  __syncthreads();
  int w = tid >> 6, lane = tid & 63;
  int b = blockIdx.x * 4 + w;
  constexpr int EX = FD - 256;
  float xv[5];
#pragma unroll
  for (int j = 0; j < 4; ++j) xv[j] = x[(size_t)b * 256 + lane + 64 * j];
  if (EX > 0) xv[4] = (lane < EX) ? prevB[(size_t)b * EX + lane] : 0.f;

#pragma unroll
  for (int s = 0; s < NS; ++s) {
    float a0 = 0.f, a1 = 0.f;
#pragma unroll
    for (int j = 0; j < 4; ++j) {
      float4 c = lds[s * FD + lane + 64 * j];
      float e = entpair(c.x, xv[j]);
      a0 = __builtin_fmaf(e, c.y, a0);
      a1 = __builtin_fmaf(-e, c.z, a1);
    }
    if (EX > 0 && lane < EX) {
      float4 c = lds[s * FD + 256 + lane];
      float e = entpair(c.x, xv[4]);
      a0 = __builtin_fmaf(e, c.y, a0);
      a1 = __builtin_fmaf(-e, c.z, a1);
    }
#pragma unroll
    for (int o = 32; o > 0; o >>= 1) {
      a0 += __shfl_xor(a0, o);
      a1 += __shfl_xor(a1, o);
    }
    if (lane == 0) {
      float2 cs = cst[s];
      float r0 = a0 + cs.x, r1 = a1 + cs.y;
      if (WRT) {
        outp[(size_t)(2 * s) * B_SZ + b] = r0;
        outp[(size_t)(2 * s + 1) * B_SZ + b] = r1;
      } else {
        outp[(size_t)b * (2 * NS) + 2 * s] = r0;
        outp[(size_t)b * (2 * NS) + 2 * s + 1] = r1;
      }
    }
  }
}

// ---------------- large levels (d=4,5): column kernel, SB stumps per block --------------
template <int SB>
__global__ __launch_bounds__(256) void ndt_level(const float* __restrict__ xT,
                                                 const float* __restrict__ xE,
                                                 const float4* __restrict__ prm,
                                                 const float2* __restrict__ cst,
                                                 int Fd, float* __restrict__ outp,
                                                 int isFinal) {
  int s0 = blockIdx.x * SB;
  int b = blockIdx.y * 256 + threadIdx.x;
  float a0[SB], a1[SB];
#pragma unroll
  for (int s = 0; s < SB; ++s) {
    float2 cs = cst[s0 + s];
    a0[s] = cs.x;
    a1[s] = cs.y;
  }
  const float* xp = xT + b;
  for (int f0 = 0; f0 < 256; f0 += 8) {
    float xv[8];
#pragma unroll
    for (int k = 0; k < 8; ++k) xv[k] = xp[(size_t)(f0 + k) * B_SZ];
#pragma unroll
    for (int k = 0; k < 8; ++k) {
#pragma unroll
      for (int s = 0; s < SB; ++s) {
        float4 c = prm[(size_t)(s0 + s) * Fd + f0 + k];
        float e = entpair(c.x, xv[k]);
        a0[s] = __builtin_fmaf(e, c.y, a0[s]);
        a1[s] = __builtin_fmaf(-e, c.z, a1[s]);
      }
    }
  }
  int ex = Fd - 256;
  const float* xq = xE + b;
  for (int f0 = 0; f0 < ex; f0 += 8) {
    float xv[8];
#pragma unroll
    for (int k = 0; k < 8; ++k) xv[k] = xq[(size_t)(f0 + k) * B_SZ];
#pragma unroll
    for (int k = 0; k < 8; ++k) {
#pragma unroll
      for (int s = 0; s < SB; ++s) {
        float4 c = prm[(size_t)(s0 + s) * Fd + 256 + f0 + k];
        float e = entpair(c.x, xv[k]);
        a0[s] = __builtin_fmaf(e, c.y, a0[s]);
        a1[s] = __builtin_fmaf(-e, c.z, a1[s]);
      }
    }
  }
  if (isFinal) {
#pragma unroll
    for (int s = 0; s < SB; ++s) {
      outp[(size_t)b * 64 + 2 * (s0 + s)] = a0[s];
      outp[(size_t)b * 64 + 2 * (s0 + s) + 1] = a1[s];
    }
  } else {
#pragma unroll
    for (int s = 0; s < SB; ++s) {
      outp[(size_t)(2 * (s0 + s)) * B_SZ + b] = a0[s];
      outp[(size_t)(2 * (s0 + s) + 1) * B_SZ + b] = a1[s];
    }
  }
}

extern "C" void kernel_launch(void* const* d_in, const int* in_sizes, int n_in,
                              void* d_out, int out_size, void* d_ws, size_t ws_size,
                              hipStream_t stream) {
  const float* x = (const float*)d_in[0];
  float* out = (float*)d_out;
  float* wsf = (float*)d_ws;

  // ws layout (float offsets)
  float* xT = wsf + 0;                  // 256 rows x 8192
  float* xE3 = wsf + 2097152;           // 16 rows x 8192 (level-3 out, transposed)
  float* xE4 = wsf + 2228224;           // 32 rows x 8192 (level-4 out, transposed)
  float* pb0 = wsf + 2490368;           // [8192][2]
  float* pb1 = wsf + 2506752;           // [8192][4]
  float* pb2 = wsf + 2539520;           // [8192][8]
  float4* prm = (float4*)(wsf + 2605056);  // 17492 float4
  float2* cst = (float2*)(wsf + 2675024);  // 63 float2

  hipLaunchKernelGGL(ndt_transpose, dim3(F_BASE / 32, B_SZ / 32), dim3(32, 8), 0,
                     stream, x, xT);

  MaskArgs ma;
  for (int d = 0; d < 6; ++d) {
    ma.fm[d] = (const float*)d_in[1 + 3 * d];
    ma.cp[d] = (const float*)d_in[2 + 3 * d];
    ma.lr[d] = (const float*)d_in[3 + 3 * d];
  }
  ma.out_masks = out;
  ma.prm = prm;
  ma.cst = cst;
  hipLaunchKernelGGL(ndt_masks, dim3(63), dim3(64), 0, stream, ma);

  const int prmOff[6] = {0, 256, 772, 1812, 3924, 8276};
  const int cstOff[6] = {0, 1, 3, 7, 15, 31};

  // d=0..3 small kernels (wave per batch row)
  hipLaunchKernelGGL((ndt_small<1, 256, 0>), dim3(B_SZ / 4), dim3(256), 0, stream,
                     x, (const float*)nullptr, prm + prmOff[0], cst + cstOff[0], pb0);
  hipLaunchKernelGGL((ndt_small<2, 258, 0>), dim3(B_SZ / 4), dim3(256), 0, stream,
                     x, pb0, prm + prmOff[1], cst + cstOff[1], pb1);
  hipLaunchKernelGGL((ndt_small<4, 260, 0>), dim3(B_SZ / 4), dim3(256), 0, stream,
                     x, pb1, prm + prmOff[2], cst + cstOff[2], pb2);
  hipLaunchKernelGGL((ndt_small<8, 264, 1>), dim3(B_SZ / 4), dim3(256), 0, stream,
                     x, pb2, prm + prmOff[3], cst + cstOff[3], xE3);

  // d=4: 16 stumps, SB=1 -> 512 blocks
  hipLaunchKernelGGL((ndt_level<1>), dim3(16, B_SZ / 256), dim3(256), 0, stream,
                     xT, xE3, prm + prmOff[4], cst + cstOff[4], 272, xE4, 0);
  // d=5: 32 stumps, SB=2 -> 512 blocks
  hipLaunchKernelGGL((ndt_level<2>), dim3(16, B_SZ / 256), dim3(256), 0, stream,
                     xT, xE4, prm + prmOff[5], cst + cstOff[5], 288, out, 1);
}